// Round 1
// baseline (3516.990 us; speedup 1.0000x reference)
//
#include <hip/hip_runtime.h>
#include <math.h>

// MS_MSA: restructured —
//   S_b = X_bᵀX_b  (per-batch 112x112)  replaces q/k materialization
//   attn from Wkᵀ S Wq blocks; M_b = attn-blockᵀ @ proj_w  (112x112/batch)
//   out = (v_inp ⊙ mask_attn) @ M_b + proj_b + dw3(gelu(dw3(v_inp)))
// Workspace (floats):
//   v_inp  29360128 | mbuf 41115648 (m1,t2,ms; later g) | mask_attn 7340032
//   S/T1/T2/Mb 4*12544 each | c1wT,c2wT 12544 each  => 312.2 MB total

#define NPX 262144      // 4*65536 total pixels
#define NB  65536       // pixels per batch
#define C   112
#define PM  122368      // 256*478 mask pixels
#define WPC 478

// ---------------- small weight transpose ([o][c] -> [c][o]) ----------------
__global__ void k_transpose_w(const float* __restrict__ a, const float* __restrict__ b,
                              float* __restrict__ at, float* __restrict__ bt) {
    int i = blockIdx.x * 256 + threadIdx.x;
    if (i < C * C) {
        int o = i / C, c = i % C;
        at[c * C + o] = a[i];
        bt[c * C + o] = b[i];
    }
}

// ---------------- per-pixel 112x112 channel-mix GEMM ----------------
// block: 256 thr (4 waves); block tile 512 px; wave -> 28 outputs; lane -> 8 px
// MODE 0: out = in @ W (+bias)      MODE 1: out = (in ⊙ mask) @ W_b (+bias)
template <int MODE>
__global__ __launch_bounds__(256, 1) void k_gemm112(
    const float* __restrict__ in, const float* __restrict__ W,
    const float* __restrict__ bias, const float* __restrict__ mask,
    float* __restrict__ out) {
    __shared__ float xT[16 * 520];
    const int tid = threadIdx.x;
    const int lane = tid & 63;
    const int o0 = __builtin_amdgcn_readfirstlane(tid >> 6) * 28;
    const long px0 = (long)blockIdx.x * 512;
    const float* Wb = W;
    if (MODE == 1) Wb = W + (int)(px0 >> 16) * (C * C);

    float acc[8][28];
#pragma unroll
    for (int p = 0; p < 8; ++p)
#pragma unroll
        for (int j = 0; j < 28; ++j) acc[p][j] = 0.0f;

    for (int cc = 0; cc < C; cc += 16) {
        __syncthreads();
        {
            const int pxl = tid >> 2;
            const int cg = (tid & 3) * 4;
#pragma unroll
            for (int r = 0; r < 8; ++r) {
                const int p = pxl + r * 64;
                const long px = px0 + p;
                float4 v = *(const float4*)(in + px * C + cc + cg);
                if (MODE == 1) {
                    const float4 m = *(const float4*)(mask + (long)((int)(px & 65535)) * C + cc + cg);
                    v.x *= m.x; v.y *= m.y; v.z *= m.z; v.w *= m.w;
                }
                xT[(cg + 0) * 520 + p] = v.x;
                xT[(cg + 1) * 520 + p] = v.y;
                xT[(cg + 2) * 520 + p] = v.z;
                xT[(cg + 3) * 520 + p] = v.w;
            }
        }
        __syncthreads();
        for (int c = 0; c < 16; ++c) {
            const float4 a = *(const float4*)&xT[c * 520 + lane * 8];
            const float4 b = *(const float4*)&xT[c * 520 + lane * 8 + 4];
            const float* wr = Wb + (cc + c) * C + o0;   // wave-uniform -> s_load
            float wloc[28];
#pragma unroll
            for (int j = 0; j < 28; ++j) wloc[j] = wr[j];
#pragma unroll
            for (int j = 0; j < 28; ++j) {
                const float w = wloc[j];
                acc[0][j] = fmaf(a.x, w, acc[0][j]);
                acc[1][j] = fmaf(a.y, w, acc[1][j]);
                acc[2][j] = fmaf(a.z, w, acc[2][j]);
                acc[3][j] = fmaf(a.w, w, acc[3][j]);
                acc[4][j] = fmaf(b.x, w, acc[4][j]);
                acc[5][j] = fmaf(b.y, w, acc[5][j]);
                acc[6][j] = fmaf(b.z, w, acc[6][j]);
                acc[7][j] = fmaf(b.w, w, acc[7][j]);
            }
        }
    }
    float bl[28];
#pragma unroll
    for (int j = 0; j < 28; ++j) bl[j] = bias ? bias[o0 + j] : 0.0f;
#pragma unroll
    for (int p = 0; p < 8; ++p) {
        const long px = px0 + (long)lane * 8 + p;
        float* dst = out + px * C + o0;
#pragma unroll
        for (int j4 = 0; j4 < 7; ++j4) {
            float4 vv;
            vv.x = acc[p][j4 * 4 + 0] + bl[j4 * 4 + 0];
            vv.y = acc[p][j4 * 4 + 1] + bl[j4 * 4 + 1];
            vv.z = acc[p][j4 * 4 + 2] + bl[j4 * 4 + 2];
            vv.w = acc[p][j4 * 4 + 3] + bl[j4 * 4 + 3];
            *(float4*)(dst + j4 * 4) = vv;
        }
    }
}

// ---------------- S_b = X_bᵀ X_b (atomic split-K syrk) ----------------
// grid 1024 = 4 batches x 256 segs; block 256 thr; lane -> c1 pair, wave -> 28 c2
__global__ __launch_bounds__(256) void k_syrk(const float* __restrict__ x, float* __restrict__ S) {
    const int blk = blockIdx.x;
    const int batch = blk >> 8;
    const int seg = blk & 255;
    const long px0 = (long)batch * NB + (long)seg * 256;
    const int lane = threadIdx.x & 63;
    const int o0 = __builtin_amdgcn_readfirstlane(threadIdx.x >> 6) * 28;
    const int c1 = lane * 2;
    const bool active = (c1 < C);
    const float* xb = x + px0 * C;
    float acc[2][28];
#pragma unroll
    for (int i = 0; i < 2; ++i)
#pragma unroll
        for (int j = 0; j < 28; ++j) acc[i][j] = 0.0f;

#pragma unroll 2
    for (int p = 0; p < 256; ++p) {
        const float* row = xb + p * C;
        float2 xv = make_float2(0.0f, 0.0f);
        if (active) xv = *(const float2*)(row + c1);
        float wloc[28];
#pragma unroll
        for (int j = 0; j < 28; ++j) wloc[j] = row[o0 + j];  // uniform -> s_load
#pragma unroll
        for (int j = 0; j < 28; ++j) {
            acc[0][j] = fmaf(xv.x, wloc[j], acc[0][j]);
            acc[1][j] = fmaf(xv.y, wloc[j], acc[1][j]);
        }
    }
    if (active) {
        float* Sb = S + batch * (C * C);
#pragma unroll
        for (int i = 0; i < 2; ++i)
#pragma unroll
            for (int j = 0; j < 28; ++j)
                atomicAdd(&Sb[(c1 + i) * C + o0 + j], acc[i][j]);
    }
}

// ---------------- mask branch: dw5x5 + sigmoid + ms (channel-major out) ----
__global__ void k_dw5(const float* __restrict__ m1, const float* __restrict__ t2,
                      const float* __restrict__ dww, const float* __restrict__ dwb,
                      float* __restrict__ ms) {
    const int px = blockIdx.x * 256 + threadIdx.x;   // < 122368
    const int r = px / WPC, w = px % WPC;
    for (int c = 0; c < C; c += 4) {
        float a0 = dwb[c], a1 = dwb[c + 1], a2 = dwb[c + 2], a3 = dwb[c + 3];
#pragma unroll
        for (int ky = 0; ky < 5; ++ky) {
            const int rr = r + ky - 2;
            if (rr < 0 || rr > 255) continue;
#pragma unroll
            for (int kx = 0; kx < 5; ++kx) {
                const int ww = w + kx - 2;
                if (ww < 0 || ww > WPC - 1) continue;
                const float4 t = *(const float4*)&t2[(long)(rr * WPC + ww) * C + c];
                const int ki = ky * 5 + kx;
                a0 = fmaf(t.x, dww[(c + 0) * 25 + ki], a0);
                a1 = fmaf(t.y, dww[(c + 1) * 25 + ki], a1);
                a2 = fmaf(t.z, dww[(c + 2) * 25 + ki], a2);
                a3 = fmaf(t.w, dww[(c + 3) * 25 + ki], a3);
            }
        }
        a0 = 1.0f / (1.0f + expf(-a0));
        a1 = 1.0f / (1.0f + expf(-a1));
        a2 = 1.0f / (1.0f + expf(-a2));
        a3 = 1.0f / (1.0f + expf(-a3));
        const float4 m = *(const float4*)&m1[(long)px * C + c];
        ms[(long)(c + 0) * PM + px] = m.x * (1.0f + a0);
        ms[(long)(c + 1) * PM + px] = m.y * (1.0f + a1);
        ms[(long)(c + 2) * PM + px] = m.z * (1.0f + a2);
        ms[(long)(c + 3) * PM + px] = m.w * (1.0f + a3);
    }
}

// ---------------- per-channel column shift + transpose to [n][c] -----------
__global__ void k_gather(const float* __restrict__ ms, float* __restrict__ mattn) {
    __shared__ float t[64][116];
    const int r = blockIdx.x >> 2;
    const int col0 = (blockIdx.x & 3) * 64;
    for (int i = threadIdx.x; i < C * 64; i += 256) {
        const int c = i >> 6, j = i & 63;
        t[j][c] = ms[(long)c * PM + r * WPC + col0 + 2 * c + j];
    }
    __syncthreads();
    for (int i = threadIdx.x; i < 64 * C; i += 256) {
        const int j = i / C, c = i % C;
        mattn[(long)(r * 256 + col0 + j) * C + c] = t[j][c];
    }
}

// ---------------- T1 = S@Wq, T2 = S@Wk (tiny) ----------------
__global__ void k_T12(const float* __restrict__ S, const float* __restrict__ Wq,
                      const float* __restrict__ Wk, float* __restrict__ T1, float* __restrict__ T2) {
    const int b = blockIdx.x, which = blockIdx.y;
    const float* Sb = S + b * (C * C);
    const float* W = which ? Wk : Wq;
    float* T = (which ? T2 : T1) + b * (C * C);
    const int i0 = blockIdx.z * 1792;
    for (int i = i0 + threadIdx.x; i < i0 + 1792; i += 256) {
        const int row = i / C, col = i % C;
        float s = 0.0f;
        for (int m = 0; m < C; ++m) s = fmaf(Sb[row * C + m], W[m * C + col], s);
        T[i] = s;
    }
}

// ---------------- attention (28x28/head) + fold into M_b -------------------
__global__ void k_attn(const float* __restrict__ T1, const float* __restrict__ T2,
                       const float* __restrict__ Wq, const float* __restrict__ Wk,
                       const float* __restrict__ rescale, const float* __restrict__ proj_w,
                       float* __restrict__ Mb) {
    __shared__ float att[28][29];
    __shared__ float nk[28], nq[28];
    const int b = blockIdx.x >> 2, h = blockIdx.x & 3;
    const float* T1b = T1 + b * (C * C);
    const float* T2b = T2 + b * (C * C);
    const int base = h * 28;
    const int tid = threadIdx.x;
    if (tid < 28) {
        const int i = base + tid;
        float s = 0.0f;
        for (int m = 0; m < C; ++m) s = fmaf(Wq[m * C + i], T1b[m * C + i], s);
        nq[tid] = fmaxf(sqrtf(fmaxf(s, 0.0f)), 1e-12f);
    } else if (tid >= 32 && tid < 60) {
        const int e = tid - 32, i = base + e;
        float s = 0.0f;
        for (int m = 0; m < C; ++m) s = fmaf(Wk[m * C + i], T2b[m * C + i], s);
        nk[e] = fmaxf(sqrtf(fmaxf(s, 0.0f)), 1e-12f);
    }
    __syncthreads();
    const float rs = rescale[h];
    for (int i = tid; i < 784; i += 256) {
        const int d = i / 28, e = i % 28;
        float s = 0.0f;
        for (int m = 0; m < C; ++m) s = fmaf(Wk[m * C + base + d], T1b[m * C + base + e], s);
        att[d][e] = s / (nk[d] * nq[e]) * rs;
    }
    __syncthreads();
    if (tid < 28) {
        float mx = -1e30f;
        for (int e = 0; e < 28; ++e) mx = fmaxf(mx, att[tid][e]);
        float sum = 0.0f;
        for (int e = 0; e < 28; ++e) { const float ex = expf(att[tid][e] - mx); att[tid][e] = ex; sum += ex; }
        const float inv = 1.0f / sum;
        for (int e = 0; e < 28; ++e) att[tid][e] *= inv;
    }
    __syncthreads();
    for (int i = tid; i < 28 * C; i += 256) {
        const int e = i / C, o = i % C;
        float s = 0.0f;
        for (int d = 0; d < 28; ++d) s = fmaf(att[d][e], proj_w[(base + d) * C + o], s);
        Mb[b * (C * C) + (base + e) * C + o] = s;
    }
}

// ---------------- pe branch: g = gelu(dw3(v)) ----------------
__global__ void k_pe1(const float* __restrict__ v, const float* __restrict__ w1, float* __restrict__ g) {
    const long px = (long)blockIdx.x * 256 + threadIdx.x;
    const int within = (int)(px & 65535);
    const long bb = px - within;
    const int r = within >> 8, w = within & 255;
    for (int c = 0; c < C; c += 4) {
        float a0 = 0, a1 = 0, a2 = 0, a3 = 0;
#pragma unroll
        for (int ky = 0; ky < 3; ++ky) {
            const int rr = r + ky - 1;
            if (rr < 0 || rr > 255) continue;
#pragma unroll
            for (int kx = 0; kx < 3; ++kx) {
                const int ww = w + kx - 1;
                if (ww < 0 || ww > 255) continue;
                const float4 t = *(const float4*)&v[(bb + (rr << 8) + ww) * C + c];
                const int ki = ky * 3 + kx;
                a0 = fmaf(t.x, w1[(c + 0) * 9 + ki], a0);
                a1 = fmaf(t.y, w1[(c + 1) * 9 + ki], a1);
                a2 = fmaf(t.z, w1[(c + 2) * 9 + ki], a2);
                a3 = fmaf(t.w, w1[(c + 3) * 9 + ki], a3);
            }
        }
        a0 = 0.5f * a0 * (1.0f + erff(a0 * 0.70710678118654752f));
        a1 = 0.5f * a1 * (1.0f + erff(a1 * 0.70710678118654752f));
        a2 = 0.5f * a2 * (1.0f + erff(a2 * 0.70710678118654752f));
        a3 = 0.5f * a3 * (1.0f + erff(a3 * 0.70710678118654752f));
        *(float4*)&g[px * C + c] = make_float4(a0, a1, a2, a3);
    }
}

// ---------------- pe branch: out += dw3(g) ----------------
__global__ void k_pe2(const float* __restrict__ g, const float* __restrict__ w2, float* __restrict__ out) {
    const long px = (long)blockIdx.x * 256 + threadIdx.x;
    const int within = (int)(px & 65535);
    const long bb = px - within;
    const int r = within >> 8, w = within & 255;
    for (int c = 0; c < C; c += 4) {
        float a0 = 0, a1 = 0, a2 = 0, a3 = 0;
#pragma unroll
        for (int ky = 0; ky < 3; ++ky) {
            const int rr = r + ky - 1;
            if (rr < 0 || rr > 255) continue;
#pragma unroll
            for (int kx = 0; kx < 3; ++kx) {
                const int ww = w + kx - 1;
                if (ww < 0 || ww > 255) continue;
                const float4 t = *(const float4*)&g[(bb + (rr << 8) + ww) * C + c];
                const int ki = ky * 3 + kx;
                a0 = fmaf(t.x, w2[(c + 0) * 9 + ki], a0);
                a1 = fmaf(t.y, w2[(c + 1) * 9 + ki], a1);
                a2 = fmaf(t.z, w2[(c + 2) * 9 + ki], a2);
                a3 = fmaf(t.w, w2[(c + 3) * 9 + ki], a3);
            }
        }
        float4 o = *(const float4*)&out[px * C + c];
        o.x += a0; o.y += a1; o.z += a2; o.w += a3;
        *(float4*)&out[px * C + c] = o;
    }
}

extern "C" void kernel_launch(void* const* d_in, const int* in_sizes, int n_in,
                              void* d_out, int out_size, void* d_ws, size_t ws_size,
                              hipStream_t stream) {
    const float* x_in    = (const float*)d_in[0];
    const float* maskp   = (const float*)d_in[1];
    const float* Wq      = (const float*)d_in[2];
    const float* Wk      = (const float*)d_in[3];
    const float* Wv      = (const float*)d_in[4];
    const float* rescale = (const float*)d_in[5];
    const float* proj_w  = (const float*)d_in[6];
    const float* proj_b  = (const float*)d_in[7];
    const float* pe_w1   = (const float*)d_in[8];
    const float* pe_w2   = (const float*)d_in[9];
    const float* c1w     = (const float*)d_in[10];
    const float* c1b     = (const float*)d_in[11];
    const float* c2w     = (const float*)d_in[12];
    const float* c2b     = (const float*)d_in[13];
    const float* dww     = (const float*)d_in[14];
    const float* dwb     = (const float*)d_in[15];

    float* ws    = (float*)d_ws;
    float* v_inp = ws;                       // 29360128
    float* mbuf  = ws + 29360128;            // 41115648 (m1,t2,ms; later g)
    float* m1    = mbuf;
    float* t2    = mbuf + 13705216;
    float* ms    = mbuf + 27410432;
    float* g     = mbuf;                     // alias (mask branch finished)
    float* mattn = ws + 70475776;            // 7340032
    float* S     = ws + 77815808;            // 50176
    float* T1    = ws + 77865984;
    float* T2    = ws + 77916160;
    float* Mb    = ws + 77966336;
    float* c1wT  = ws + 78016512;
    float* c2wT  = ws + 78029056;            // end 78041600 floats (312.2 MB)

    hipMemsetAsync(S, 0, 4 * C * C * sizeof(float), stream);
    k_transpose_w<<<49, 256, 0, stream>>>(c1w, c2w, c1wT, c2wT);
    k_gemm112<0><<<512, 256, 0, stream>>>(x_in, Wv, nullptr, nullptr, v_inp);
    k_syrk<<<1024, 256, 0, stream>>>(x_in, S);
    k_gemm112<0><<<239, 256, 0, stream>>>(maskp, c1wT, c1b, nullptr, m1);
    k_gemm112<0><<<239, 256, 0, stream>>>(m1, c2wT, c2b, nullptr, t2);
    k_dw5<<<478, 256, 0, stream>>>(m1, t2, dww, dwb, ms);
    k_gather<<<1024, 256, 0, stream>>>(ms, mattn);
    k_T12<<<dim3(4, 2, 7), 256, 0, stream>>>(S, Wq, Wk, T1, T2);
    k_attn<<<16, 256, 0, stream>>>(T1, T2, Wq, Wk, rescale, proj_w, Mb);
    k_pe1<<<1024, 256, 0, stream>>>(v_inp, pe_w1, g);
    k_gemm112<1><<<512, 256, 0, stream>>>(v_inp, Mb, proj_b, mattn, (float*)d_out);
    k_pe2<<<1024, 256, 0, stream>>>(g, pe_w2, (float*)d_out);
    (void)in_sizes; (void)n_in; (void)out_size; (void)ws_size;
}

// Round 2
// 1202.675 us; speedup vs baseline: 2.9243x; 2.9243x over previous
//
#include <hip/hip_runtime.h>
#include <math.h>

// MS_MSA restructured:
//   S_b = X_bᵀX_b (112x112/batch) replaces q/k materialization
//   attn from Wkᵀ S Wq blocks; M_b = attn-blockᵀ @ proj_w
//   out = (v ⊙ mask_attn) @ M_b + proj_b + dw3(gelu(dw3(v)))
// R1 fixes: syrk partials+reduce (no atomics), gemm112 4px/lane (no spill),
// coalesced stencil kernels (lane = channel quad).

#define NPX 262144
#define NB  65536
#define C   112
#define PM  122368
#define WPC 478

// ---------------- small weight transpose ([o][c] -> [c][o]) ----------------
__global__ void k_transpose_w(const float* __restrict__ a, const float* __restrict__ b,
                              float* __restrict__ at, float* __restrict__ bt) {
    int i = blockIdx.x * 256 + threadIdx.x;
    if (i < C * C) {
        int o = i / C, c = i % C;
        at[c * C + o] = a[i];
        bt[c * C + o] = b[i];
    }
}

// ---------------- per-pixel 112x112 channel-mix GEMM ----------------
// block 256 thr (4 waves); tile 256 px; wave -> 28 outs; lane -> 4 px
// MODE 0: out = in @ W (+bias)   MODE 1: out = (in ⊙ mask) @ W_b (+bias)
template <int MODE>
__global__ __launch_bounds__(256, 2) void k_gemm112(
    const float* __restrict__ in, const float* __restrict__ W,
    const float* __restrict__ bias, const float* __restrict__ mask,
    float* __restrict__ out) {
    __shared__ float xT[16 * 260];
    const int tid = threadIdx.x;
    const int lane = tid & 63;
    const int o0 = __builtin_amdgcn_readfirstlane(tid >> 6) * 28;
    const long px0 = (long)blockIdx.x * 256;
    const float* Wb = W;
    if (MODE == 1) Wb = W + (int)(px0 >> 16) * (C * C);

    float acc[4][28];
#pragma unroll
    for (int p = 0; p < 4; ++p)
#pragma unroll
        for (int j = 0; j < 28; ++j) acc[p][j] = 0.0f;

    for (int cc = 0; cc < C; cc += 16) {
        __syncthreads();
        {
            const int pxl = tid >> 2;
            const int cg = (tid & 3) * 4;
#pragma unroll
            for (int r = 0; r < 4; ++r) {
                const int p = pxl + r * 64;
                const long px = px0 + p;
                float4 v = *(const float4*)(in + px * C + cc + cg);
                if (MODE == 1) {
                    const float4 m = *(const float4*)(mask + (long)((int)(px & 65535)) * C + cc + cg);
                    v.x *= m.x; v.y *= m.y; v.z *= m.z; v.w *= m.w;
                }
                xT[(cg + 0) * 260 + p] = v.x;
                xT[(cg + 1) * 260 + p] = v.y;
                xT[(cg + 2) * 260 + p] = v.z;
                xT[(cg + 3) * 260 + p] = v.w;
            }
        }
        __syncthreads();
#pragma unroll
        for (int c = 0; c < 16; ++c) {
            const float4 a = *(const float4*)&xT[c * 260 + lane * 4];
            const float* wr = Wb + (cc + c) * C + o0;   // wave-uniform -> s_load
            float wl[28];
#pragma unroll
            for (int j = 0; j < 28; ++j) wl[j] = wr[j];
#pragma unroll
            for (int j = 0; j < 28; ++j) {
                const float w = wl[j];
                acc[0][j] = fmaf(a.x, w, acc[0][j]);
                acc[1][j] = fmaf(a.y, w, acc[1][j]);
                acc[2][j] = fmaf(a.z, w, acc[2][j]);
                acc[3][j] = fmaf(a.w, w, acc[3][j]);
            }
        }
    }
    float bl[28];
#pragma unroll
    for (int j = 0; j < 28; ++j) bl[j] = bias ? bias[o0 + j] : 0.0f;
#pragma unroll
    for (int p = 0; p < 4; ++p) {
        const long px = px0 + (long)lane * 4 + p;
        float* dst = out + px * C + o0;
#pragma unroll
        for (int j4 = 0; j4 < 7; ++j4) {
            float4 vv;
            vv.x = acc[p][j4 * 4 + 0] + bl[j4 * 4 + 0];
            vv.y = acc[p][j4 * 4 + 1] + bl[j4 * 4 + 1];
            vv.z = acc[p][j4 * 4 + 2] + bl[j4 * 4 + 2];
            vv.w = acc[p][j4 * 4 + 3] + bl[j4 * 4 + 3];
            *(float4*)(dst + j4 * 4) = vv;
        }
    }
}

// ---------------- S_b = X_bᵀ X_b: LDS-tiled partials, no atomics ----------
// grid 512 = 4 batches x 128 segs; block 256 (16x16); 7x7 out/thread; 512 px/blk
__global__ __launch_bounds__(256, 2) void k_syrk(const float* __restrict__ x,
                                                 float* __restrict__ part) {
    __shared__ float tile[16 * C];
    const int batch = blockIdx.x >> 7, seg = blockIdx.x & 127;
    const float* xb = x + ((long)batch * NB + (long)seg * 512) * C;
    const int ty = threadIdx.x >> 4, tx = threadIdx.x & 15;
    float acc[7][7];
#pragma unroll
    for (int i = 0; i < 7; ++i)
#pragma unroll
        for (int j = 0; j < 7; ++j) acc[i][j] = 0.0f;

    for (int ph = 0; ph < 32; ++ph) {
        __syncthreads();
        for (int i = threadIdx.x; i < 16 * C; i += 256)
            tile[i] = xb[ph * 16 * C + i];
        __syncthreads();
#pragma unroll 4
        for (int p = 0; p < 16; ++p) {
            float a[7], b[7];
#pragma unroll
            for (int i = 0; i < 7; ++i) a[i] = tile[p * C + ty * 7 + i];
#pragma unroll
            for (int j = 0; j < 7; ++j) b[j] = tile[p * C + tx * 7 + j];
#pragma unroll
            for (int i = 0; i < 7; ++i)
#pragma unroll
                for (int j = 0; j < 7; ++j)
                    acc[i][j] = fmaf(a[i], b[j], acc[i][j]);
        }
    }
    float* pb = part + (long)blockIdx.x * (C * C);
#pragma unroll
    for (int i = 0; i < 7; ++i)
#pragma unroll
        for (int j = 0; j < 7; ++j)
            pb[(ty * 7 + i) * C + tx * 7 + j] = acc[i][j];
}

// ---------------- sum 128 partials per batch ----------------
__global__ void k_syrk_reduce(const float* __restrict__ part, float* __restrict__ S) {
    const int b = blockIdx.x;
    const int i = blockIdx.y * 256 + threadIdx.x;  // < 12544
    const float* p = part + (long)b * 128 * (C * C) + i;
    float s = 0.0f;
    for (int k = 0; k < 128; ++k) s += p[(long)k * (C * C)];
    S[b * (C * C) + i] = s;
}

// ---------------- mask branch: dw5x5 + sigmoid + ms (channel-major out) ----
// block: 8 px x 32 lanes (28 active = channel quads); coalesced
__global__ void k_dw5(const float* __restrict__ m1, const float* __restrict__ t2,
                      const float* __restrict__ dww, const float* __restrict__ dwb,
                      float* __restrict__ ms) {
    const int px = blockIdx.x * 8 + (threadIdx.x >> 5);
    const int cs = threadIdx.x & 31;
    if (cs >= 28) return;
    const int c = cs * 4;
    const int r = px / WPC, w = px % WPC;
    float wv[4][25];
#pragma unroll
    for (int k = 0; k < 4; ++k)
#pragma unroll
        for (int t = 0; t < 25; ++t) wv[k][t] = dww[(c + k) * 25 + t];
    float a0 = dwb[c], a1 = dwb[c + 1], a2 = dwb[c + 2], a3 = dwb[c + 3];
#pragma unroll
    for (int ky = 0; ky < 5; ++ky) {
        const int rr = r + ky - 2;
        if (rr < 0 || rr > 255) continue;
#pragma unroll
        for (int kx = 0; kx < 5; ++kx) {
            const int ww = w + kx - 2;
            if (ww < 0 || ww > WPC - 1) continue;
            const float4 t = *(const float4*)&t2[(long)(rr * WPC + ww) * C + c];
            const int ki = ky * 5 + kx;
            a0 = fmaf(t.x, wv[0][ki], a0);
            a1 = fmaf(t.y, wv[1][ki], a1);
            a2 = fmaf(t.z, wv[2][ki], a2);
            a3 = fmaf(t.w, wv[3][ki], a3);
        }
    }
    a0 = 1.0f / (1.0f + expf(-a0));
    a1 = 1.0f / (1.0f + expf(-a1));
    a2 = 1.0f / (1.0f + expf(-a2));
    a3 = 1.0f / (1.0f + expf(-a3));
    const float4 m = *(const float4*)&m1[(long)px * C + c];
    ms[(long)(c + 0) * PM + px] = m.x * (1.0f + a0);
    ms[(long)(c + 1) * PM + px] = m.y * (1.0f + a1);
    ms[(long)(c + 2) * PM + px] = m.z * (1.0f + a2);
    ms[(long)(c + 3) * PM + px] = m.w * (1.0f + a3);
}

// ---------------- per-channel column shift + transpose to [n][c] -----------
__global__ void k_gather(const float* __restrict__ ms, float* __restrict__ mattn) {
    __shared__ float t[64][116];
    const int r = blockIdx.x >> 2;
    const int col0 = (blockIdx.x & 3) * 64;
    for (int i = threadIdx.x; i < C * 64; i += 256) {
        const int c = i >> 6, j = i & 63;
        t[j][c] = ms[(long)c * PM + r * WPC + col0 + 2 * c + j];
    }
    __syncthreads();
    for (int i = threadIdx.x; i < 64 * C; i += 256) {
        const int j = i / C, c = i % C;
        mattn[(long)(r * 256 + col0 + j) * C + c] = t[j][c];
    }
}

// ---------------- T1 = S@Wq, T2 = S@Wk (tiny) ----------------
__global__ void k_T12(const float* __restrict__ S, const float* __restrict__ Wq,
                      const float* __restrict__ Wk, float* __restrict__ T1, float* __restrict__ T2) {
    const int b = blockIdx.x, which = blockIdx.y;
    const float* Sb = S + b * (C * C);
    const float* W = which ? Wk : Wq;
    float* T = (which ? T2 : T1) + b * (C * C);
    const int i0 = blockIdx.z * 1792;
    for (int i = i0 + threadIdx.x; i < i0 + 1792; i += 256) {
        const int row = i / C, col = i % C;
        float s = 0.0f;
        for (int m = 0; m < C; ++m) s = fmaf(Sb[row * C + m], W[m * C + col], s);
        T[i] = s;
    }
}

// ---------------- attention (28x28/head) + fold into M_b -------------------
__global__ void k_attn(const float* __restrict__ T1, const float* __restrict__ T2,
                       const float* __restrict__ Wq, const float* __restrict__ Wk,
                       const float* __restrict__ rescale, const float* __restrict__ proj_w,
                       float* __restrict__ Mb) {
    __shared__ float att[28][29];
    __shared__ float nk[28], nq[28];
    const int b = blockIdx.x >> 2, h = blockIdx.x & 3;
    const float* T1b = T1 + b * (C * C);
    const float* T2b = T2 + b * (C * C);
    const int base = h * 28;
    const int tid = threadIdx.x;
    if (tid < 28) {
        const int i = base + tid;
        float s = 0.0f;
        for (int m = 0; m < C; ++m) s = fmaf(Wq[m * C + i], T1b[m * C + i], s);
        nq[tid] = fmaxf(sqrtf(fmaxf(s, 0.0f)), 1e-12f);
    } else if (tid >= 32 && tid < 60) {
        const int e = tid - 32, i = base + e;
        float s = 0.0f;
        for (int m = 0; m < C; ++m) s = fmaf(Wk[m * C + i], T2b[m * C + i], s);
        nk[e] = fmaxf(sqrtf(fmaxf(s, 0.0f)), 1e-12f);
    }
    __syncthreads();
    const float rs = rescale[h];
    for (int i = tid; i < 784; i += 256) {
        const int d = i / 28, e = i % 28;
        float s = 0.0f;
        for (int m = 0; m < C; ++m) s = fmaf(Wk[m * C + base + d], T1b[m * C + base + e], s);
        att[d][e] = s / (nk[d] * nq[e]) * rs;
    }
    __syncthreads();
    if (tid < 28) {
        float mx = -1e30f;
        for (int e = 0; e < 28; ++e) mx = fmaxf(mx, att[tid][e]);
        float sum = 0.0f;
        for (int e = 0; e < 28; ++e) { const float ex = expf(att[tid][e] - mx); att[tid][e] = ex; sum += ex; }
        const float inv = 1.0f / sum;
        for (int e = 0; e < 28; ++e) att[tid][e] *= inv;
    }
    __syncthreads();
    for (int i = tid; i < 28 * C; i += 256) {
        const int e = i / C, o = i % C;
        float s = 0.0f;
        for (int d = 0; d < 28; ++d) s = fmaf(att[d][e], proj_w[(base + d) * C + o], s);
        Mb[b * (C * C) + (base + e) * C + o] = s;
    }
}

// ---------------- pe branch: g = gelu(dw3(v)) — coalesced ----------------
__global__ void k_pe1(const float* __restrict__ v, const float* __restrict__ w1, float* __restrict__ g) {
    const long px = (long)blockIdx.x * 8 + (threadIdx.x >> 5);
    const int cs = threadIdx.x & 31;
    if (cs >= 28) return;
    const int c = cs * 4;
    const int within = (int)(px & 65535);
    const long bb = px - within;
    const int r = within >> 8, w = within & 255;
    float wv[4][9];
#pragma unroll
    for (int k = 0; k < 4; ++k)
#pragma unroll
        for (int t = 0; t < 9; ++t) wv[k][t] = w1[(c + k) * 9 + t];
    float a0 = 0, a1 = 0, a2 = 0, a3 = 0;
#pragma unroll
    for (int ky = 0; ky < 3; ++ky) {
        const int rr = r + ky - 1;
        if (rr < 0 || rr > 255) continue;
#pragma unroll
        for (int kx = 0; kx < 3; ++kx) {
            const int ww = w + kx - 1;
            if (ww < 0 || ww > 255) continue;
            const float4 t = *(const float4*)&v[(bb + (rr << 8) + ww) * C + c];
            const int ki = ky * 3 + kx;
            a0 = fmaf(t.x, wv[0][ki], a0);
            a1 = fmaf(t.y, wv[1][ki], a1);
            a2 = fmaf(t.z, wv[2][ki], a2);
            a3 = fmaf(t.w, wv[3][ki], a3);
        }
    }
    a0 = 0.5f * a0 * (1.0f + erff(a0 * 0.70710678118654752f));
    a1 = 0.5f * a1 * (1.0f + erff(a1 * 0.70710678118654752f));
    a2 = 0.5f * a2 * (1.0f + erff(a2 * 0.70710678118654752f));
    a3 = 0.5f * a3 * (1.0f + erff(a3 * 0.70710678118654752f));
    *(float4*)&g[px * C + c] = make_float4(a0, a1, a2, a3);
}

// ---------------- pe branch: out += dw3(g) — coalesced ----------------
__global__ void k_pe2(const float* __restrict__ g, const float* __restrict__ w2, float* __restrict__ out) {
    const long px = (long)blockIdx.x * 8 + (threadIdx.x >> 5);
    const int cs = threadIdx.x & 31;
    if (cs >= 28) return;
    const int c = cs * 4;
    const int within = (int)(px & 65535);
    const long bb = px - within;
    const int r = within >> 8, w = within & 255;
    float wv[4][9];
#pragma unroll
    for (int k = 0; k < 4; ++k)
#pragma unroll
        for (int t = 0; t < 9; ++t) wv[k][t] = w2[(c + k) * 9 + t];
    float a0 = 0, a1 = 0, a2 = 0, a3 = 0;
#pragma unroll
    for (int ky = 0; ky < 3; ++ky) {
        const int rr = r + ky - 1;
        if (rr < 0 || rr > 255) continue;
#pragma unroll
        for (int kx = 0; kx < 3; ++kx) {
            const int ww = w + kx - 1;
            if (ww < 0 || ww > 255) continue;
            const float4 t = *(const float4*)&g[(bb + (rr << 8) + ww) * C + c];
            const int ki = ky * 3 + kx;
            a0 = fmaf(t.x, wv[0][ki], a0);
            a1 = fmaf(t.y, wv[1][ki], a1);
            a2 = fmaf(t.z, wv[2][ki], a2);
            a3 = fmaf(t.w, wv[3][ki], a3);
        }
    }
    float4 o = *(const float4*)&out[px * C + c];
    o.x += a0; o.y += a1; o.z += a2; o.w += a3;
    *(float4*)&out[px * C + c] = o;
}

extern "C" void kernel_launch(void* const* d_in, const int* in_sizes, int n_in,
                              void* d_out, int out_size, void* d_ws, size_t ws_size,
                              hipStream_t stream) {
    const float* x_in    = (const float*)d_in[0];
    const float* maskp   = (const float*)d_in[1];
    const float* Wq      = (const float*)d_in[2];
    const float* Wk      = (const float*)d_in[3];
    const float* Wv      = (const float*)d_in[4];
    const float* rescale = (const float*)d_in[5];
    const float* proj_w  = (const float*)d_in[6];
    const float* proj_b  = (const float*)d_in[7];
    const float* pe_w1   = (const float*)d_in[8];
    const float* pe_w2   = (const float*)d_in[9];
    const float* c1w     = (const float*)d_in[10];
    const float* c1b     = (const float*)d_in[11];
    const float* c2w     = (const float*)d_in[12];
    const float* c2b     = (const float*)d_in[13];
    const float* dww     = (const float*)d_in[14];
    const float* dwb     = (const float*)d_in[15];

    float* ws    = (float*)d_ws;
    float* v_inp = ws;                       // 29360128
    float* mbuf  = ws + 29360128;            // 41115648 (m1,t2,ms; later g)
    float* m1    = mbuf;
    float* t2    = mbuf + 13705216;
    float* ms    = mbuf + 27410432;
    float* g     = mbuf;                     // alias (mask branch finished)
    float* mattn = ws + 70475776;            // 7340032 (also syrk partials early)
    float* part  = mattn;                    // 512*12544 = 6422528 <= 7340032
    float* S     = ws + 77815808;
    float* T1    = ws + 77865984;
    float* T2    = ws + 77916160;
    float* Mb    = ws + 77966336;
    float* c1wT  = ws + 78016512;
    float* c2wT  = ws + 78029056;            // end 78041600 floats (312.2 MB)

    k_transpose_w<<<49, 256, 0, stream>>>(c1w, c2w, c1wT, c2wT);
    k_gemm112<0><<<1024, 256, 0, stream>>>(x_in, Wv, nullptr, nullptr, v_inp);
    k_syrk<<<512, 256, 0, stream>>>(x_in, part);
    k_syrk_reduce<<<dim3(4, 49), 256, 0, stream>>>(part, S);
    k_gemm112<0><<<478, 256, 0, stream>>>(maskp, c1wT, c1b, nullptr, m1);
    k_gemm112<0><<<478, 256, 0, stream>>>(m1, c2wT, c2b, nullptr, t2);
    k_dw5<<<15296, 256, 0, stream>>>(m1, t2, dww, dwb, ms);
    k_gather<<<1024, 256, 0, stream>>>(ms, mattn);
    k_T12<<<dim3(4, 2, 7), 256, 0, stream>>>(S, Wq, Wk, T1, T2);
    k_attn<<<16, 256, 0, stream>>>(T1, T2, Wq, Wk, rescale, proj_w, Mb);
    k_pe1<<<32768, 256, 0, stream>>>(v_inp, pe_w1, g);
    k_gemm112<1><<<1024, 256, 0, stream>>>(v_inp, Mb, proj_b, mattn, (float*)d_out);
    k_pe2<<<32768, 256, 0, stream>>>(g, pe_w2, (float*)d_out);
    (void)in_sizes; (void)n_in; (void)out_size; (void)ws_size;
}

// Round 3
// 1081.008 us; speedup vs baseline: 3.2534x; 1.1126x over previous
//
#include <hip/hip_runtime.h>
#include <math.h>

// MS_MSA restructured:
//   S_b = X_bᵀX_b (112x112/batch) replaces q/k materialization
//   attn from Wkᵀ S Wq blocks; M_b = attn-blockᵀ @ proj_w
//   out = (v ⊙ mask_attn) @ M_b + proj_b + dw3(gelu(dw3(v)))
// R2 fixes: stencils use 4px/thread sliding windows + transposed [tap][ch]
// weights (1 b128/tap) + lb(256,4); syrk back to s_load inner (no DS), partials.

#define NPX 262144
#define NB  65536
#define C   112
#define PM  122368
#define WPC 478

// ------------- weight transposes: [o][c]->[c][o], [ch][tap]->[tap][ch] -----
__global__ void k_transpose_w(const float* __restrict__ a, const float* __restrict__ b,
                              const float* __restrict__ dw, const float* __restrict__ p1,
                              const float* __restrict__ p2,
                              float* __restrict__ at, float* __restrict__ bt,
                              float* __restrict__ dwt, float* __restrict__ p1t,
                              float* __restrict__ p2t) {
    const int i = blockIdx.x * 256 + threadIdx.x;
    if (i < C * C) {
        const int o = i / C, cc = i % C;
        at[cc * C + o] = a[i];
        bt[cc * C + o] = b[i];
    }
    if (i < 25 * C) {
        const int t = i / C, ch = i % C;
        dwt[i] = dw[ch * 25 + t];
    }
    if (i < 9 * C) {
        const int t = i / C, ch = i % C;
        p1t[i] = p1[ch * 9 + t];
        p2t[i] = p2[ch * 9 + t];
    }
}

// ---------------- per-pixel 112x112 channel-mix GEMM ----------------
// block 256 thr (4 waves); tile 256 px; wave -> 28 outs; lane -> 4 px
template <int MODE>
__global__ __launch_bounds__(256, 2) void k_gemm112(
    const float* __restrict__ in, const float* __restrict__ W,
    const float* __restrict__ bias, const float* __restrict__ mask,
    float* __restrict__ out) {
    __shared__ float xT[16 * 260];
    const int tid = threadIdx.x;
    const int lane = tid & 63;
    const int o0 = __builtin_amdgcn_readfirstlane(tid >> 6) * 28;
    const long px0 = (long)blockIdx.x * 256;
    const float* Wb = W;
    if (MODE == 1) Wb = W + (int)(px0 >> 16) * (C * C);

    float acc[4][28];
#pragma unroll
    for (int p = 0; p < 4; ++p)
#pragma unroll
        for (int j = 0; j < 28; ++j) acc[p][j] = 0.0f;

    for (int cc = 0; cc < C; cc += 16) {
        __syncthreads();
        {
            const int pxl = tid >> 2;
            const int cg = (tid & 3) * 4;
#pragma unroll
            for (int r = 0; r < 4; ++r) {
                const int p = pxl + r * 64;
                const long px = px0 + p;
                float4 v = *(const float4*)(in + px * C + cc + cg);
                if (MODE == 1) {
                    const float4 m = *(const float4*)(mask + (long)((int)(px & 65535)) * C + cc + cg);
                    v.x *= m.x; v.y *= m.y; v.z *= m.z; v.w *= m.w;
                }
                xT[(cg + 0) * 260 + p] = v.x;
                xT[(cg + 1) * 260 + p] = v.y;
                xT[(cg + 2) * 260 + p] = v.z;
                xT[(cg + 3) * 260 + p] = v.w;
            }
        }
        __syncthreads();
#pragma unroll
        for (int c = 0; c < 16; ++c) {
            const float4 a = *(const float4*)&xT[c * 260 + lane * 4];
            const float* wr = Wb + (cc + c) * C + o0;   // wave-uniform -> s_load
            float wl[28];
#pragma unroll
            for (int j = 0; j < 28; ++j) wl[j] = wr[j];
#pragma unroll
            for (int j = 0; j < 28; ++j) {
                const float w = wl[j];
                acc[0][j] = fmaf(a.x, w, acc[0][j]);
                acc[1][j] = fmaf(a.y, w, acc[1][j]);
                acc[2][j] = fmaf(a.z, w, acc[2][j]);
                acc[3][j] = fmaf(a.w, w, acc[3][j]);
            }
        }
    }
    float bl[28];
#pragma unroll
    for (int j = 0; j < 28; ++j) bl[j] = bias ? bias[o0 + j] : 0.0f;
#pragma unroll
    for (int p = 0; p < 4; ++p) {
        const long px = px0 + (long)lane * 4 + p;
        float* dst = out + px * C + o0;
#pragma unroll
        for (int j4 = 0; j4 < 7; ++j4) {
            float4 vv;
            vv.x = acc[p][j4 * 4 + 0] + bl[j4 * 4 + 0];
            vv.y = acc[p][j4 * 4 + 1] + bl[j4 * 4 + 1];
            vv.z = acc[p][j4 * 4 + 2] + bl[j4 * 4 + 2];
            vv.w = acc[p][j4 * 4 + 3] + bl[j4 * 4 + 3];
            *(float4*)(dst + j4 * 4) = vv;
        }
    }
}

// ---------------- S_b = X_bᵀ X_b: s_load inner, partials, no atomics -------
// grid 512 = 4 batches x 128 segs of 512 px; lane -> c pair, wave -> 28 cols
__global__ __launch_bounds__(256) void k_syrk(const float* __restrict__ x,
                                              float* __restrict__ part) {
    const int blk = blockIdx.x;
    const int batch = blk >> 7, seg = blk & 127;
    const long px0 = (long)batch * NB + (long)seg * 512;
    const int lane = threadIdx.x & 63;
    const int o0 = __builtin_amdgcn_readfirstlane(threadIdx.x >> 6) * 28;
    const int c1 = lane * 2;
    const bool active = (c1 < C);
    const float* xb = x + px0 * C;
    float acc[2][28];
#pragma unroll
    for (int i = 0; i < 2; ++i)
#pragma unroll
        for (int j = 0; j < 28; ++j) acc[i][j] = 0.0f;

#pragma unroll 2
    for (int p = 0; p < 512; ++p) {
        const float* row = xb + p * C;
        float2 xv = make_float2(0.0f, 0.0f);
        if (active) xv = *(const float2*)(row + c1);
        float wl[28];
#pragma unroll
        for (int j = 0; j < 28; ++j) wl[j] = row[o0 + j];   // uniform -> s_load
#pragma unroll
        for (int j = 0; j < 28; ++j) {
            acc[0][j] = fmaf(xv.x, wl[j], acc[0][j]);
            acc[1][j] = fmaf(xv.y, wl[j], acc[1][j]);
        }
    }
    if (active) {
        float* pb = part + (long)blk * (C * C);
#pragma unroll
        for (int i = 0; i < 2; ++i)
#pragma unroll
            for (int j = 0; j < 28; ++j)
                pb[(c1 + i) * C + o0 + j] = acc[i][j];
    }
}

// ---------------- sum 128 partials per batch ----------------
__global__ void k_syrk_reduce(const float* __restrict__ part, float* __restrict__ S) {
    const int b = blockIdx.x;
    const int i = blockIdx.y * 256 + threadIdx.x;  // < 12544
    const float* p = part + (long)b * 128 * (C * C) + i;
    float s = 0.0f;
    for (int k = 0; k < 128; ++k) s += p[(long)k * (C * C)];
    S[b * (C * C) + i] = s;
}

// ------------- mask branch: dw5x5 + sigmoid + ms (channel-major out) -------
// thread: 4 consecutive-col px x 1 channel-quad; sliding 8x5 float4 window
__global__ __launch_bounds__(256, 4) void k_dw5(
    const float* __restrict__ m1, const float* __restrict__ t2,
    const float* __restrict__ dwwT, const float* __restrict__ dwb,
    float* __restrict__ ms) {
    const int g = threadIdx.x >> 5, cs = threadIdx.x & 31;
    if (cs >= 28) return;
    const int c = cs * 4;
    const int px0 = blockIdx.x * 32 + g * 4;
    const int r = px0 / WPC;
    const int w0 = px0 - r * WPC;
    const float4 b4 = *(const float4*)&dwb[c];
    float4 acc[4];
#pragma unroll
    for (int p = 0; p < 4; ++p) acc[p] = b4;

    if (w0 >= 2 && w0 <= 472) {
#pragma unroll
        for (int ky = 0; ky < 5; ++ky) {
            const int rr = r + ky - 2;
            if (rr < 0 || rr > 255) continue;
            const float* row = t2 + (long)(rr * WPC + w0 - 2) * C + c;
            float4 win[8];
#pragma unroll
            for (int k = 0; k < 8; ++k) win[k] = *(const float4*)(row + k * C);
#pragma unroll
            for (int kx = 0; kx < 5; ++kx) {
                const float4 wt = *(const float4*)&dwwT[(ky * 5 + kx) * C + c];
#pragma unroll
                for (int p = 0; p < 4; ++p) {
                    acc[p].x = fmaf(win[p + kx].x, wt.x, acc[p].x);
                    acc[p].y = fmaf(win[p + kx].y, wt.y, acc[p].y);
                    acc[p].z = fmaf(win[p + kx].z, wt.z, acc[p].z);
                    acc[p].w = fmaf(win[p + kx].w, wt.w, acc[p].w);
                }
            }
        }
    } else {
#pragma unroll
        for (int p = 0; p < 4; ++p) {
            const int px = px0 + p;
            const int r2 = px / WPC, w2 = px - r2 * WPC;
            for (int ky = 0; ky < 5; ++ky) {
                const int rr = r2 + ky - 2;
                if (rr < 0 || rr > 255) continue;
                for (int kx = 0; kx < 5; ++kx) {
                    const int ww = w2 + kx - 2;
                    if (ww < 0 || ww > WPC - 1) continue;
                    const float4 t = *(const float4*)&t2[(long)(rr * WPC + ww) * C + c];
                    const float4 wt = *(const float4*)&dwwT[(ky * 5 + kx) * C + c];
                    acc[p].x = fmaf(t.x, wt.x, acc[p].x);
                    acc[p].y = fmaf(t.y, wt.y, acc[p].y);
                    acc[p].z = fmaf(t.z, wt.z, acc[p].z);
                    acc[p].w = fmaf(t.w, wt.w, acc[p].w);
                }
            }
        }
    }
#pragma unroll
    for (int p = 0; p < 4; ++p) {
        const int px = px0 + p;
        const float a0 = 1.0f / (1.0f + expf(-acc[p].x));
        const float a1 = 1.0f / (1.0f + expf(-acc[p].y));
        const float a2 = 1.0f / (1.0f + expf(-acc[p].z));
        const float a3 = 1.0f / (1.0f + expf(-acc[p].w));
        const float4 m = *(const float4*)&m1[(long)px * C + c];
        ms[(long)(c + 0) * PM + px] = m.x * (1.0f + a0);
        ms[(long)(c + 1) * PM + px] = m.y * (1.0f + a1);
        ms[(long)(c + 2) * PM + px] = m.z * (1.0f + a2);
        ms[(long)(c + 3) * PM + px] = m.w * (1.0f + a3);
    }
}

// ---------------- per-channel column shift + transpose to [n][c] -----------
__global__ void k_gather(const float* __restrict__ ms, float* __restrict__ mattn) {
    __shared__ float t[64][116];
    const int r = blockIdx.x >> 2;
    const int col0 = (blockIdx.x & 3) * 64;
    for (int i = threadIdx.x; i < C * 64; i += 256) {
        const int c = i >> 6, j = i & 63;
        t[j][c] = ms[(long)c * PM + r * WPC + col0 + 2 * c + j];
    }
    __syncthreads();
    for (int i = threadIdx.x; i < 64 * C; i += 256) {
        const int j = i / C, c = i % C;
        mattn[(long)(r * 256 + col0 + j) * C + c] = t[j][c];
    }
}

// ---------------- T1 = S@Wq, T2 = S@Wk (tiny) ----------------
__global__ void k_T12(const float* __restrict__ S, const float* __restrict__ Wq,
                      const float* __restrict__ Wk, float* __restrict__ T1, float* __restrict__ T2) {
    const int b = blockIdx.x, which = blockIdx.y;
    const float* Sb = S + b * (C * C);
    const float* W = which ? Wk : Wq;
    float* T = (which ? T2 : T1) + b * (C * C);
    const int i0 = blockIdx.z * 1792;
    for (int i = i0 + threadIdx.x; i < i0 + 1792; i += 256) {
        const int row = i / C, col = i % C;
        float s = 0.0f;
        for (int m = 0; m < C; ++m) s = fmaf(Sb[row * C + m], W[m * C + col], s);
        T[i] = s;
    }
}

// ---------------- attention (28x28/head) + fold into M_b -------------------
__global__ void k_attn(const float* __restrict__ T1, const float* __restrict__ T2,
                       const float* __restrict__ Wq, const float* __restrict__ Wk,
                       const float* __restrict__ rescale, const float* __restrict__ proj_w,
                       float* __restrict__ Mb) {
    __shared__ float att[28][29];
    __shared__ float nk[28], nq[28];
    const int b = blockIdx.x >> 2, h = blockIdx.x & 3;
    const float* T1b = T1 + b * (C * C);
    const float* T2b = T2 + b * (C * C);
    const int base = h * 28;
    const int tid = threadIdx.x;
    if (tid < 28) {
        const int i = base + tid;
        float s = 0.0f;
        for (int m = 0; m < C; ++m) s = fmaf(Wq[m * C + i], T1b[m * C + i], s);
        nq[tid] = fmaxf(sqrtf(fmaxf(s, 0.0f)), 1e-12f);
    } else if (tid >= 32 && tid < 60) {
        const int e = tid - 32, i = base + e;
        float s = 0.0f;
        for (int m = 0; m < C; ++m) s = fmaf(Wk[m * C + i], T2b[m * C + i], s);
        nk[e] = fmaxf(sqrtf(fmaxf(s, 0.0f)), 1e-12f);
    }
    __syncthreads();
    const float rs = rescale[h];
    for (int i = tid; i < 784; i += 256) {
        const int d = i / 28, e = i % 28;
        float s = 0.0f;
        for (int m = 0; m < C; ++m) s = fmaf(Wk[m * C + base + d], T1b[m * C + base + e], s);
        att[d][e] = s / (nk[d] * nq[e]) * rs;
    }
    __syncthreads();
    if (tid < 28) {
        float mx = -1e30f;
        for (int e = 0; e < 28; ++e) mx = fmaxf(mx, att[tid][e]);
        float sum = 0.0f;
        for (int e = 0; e < 28; ++e) { const float ex = expf(att[tid][e] - mx); att[tid][e] = ex; sum += ex; }
        const float inv = 1.0f / sum;
        for (int e = 0; e < 28; ++e) att[tid][e] *= inv;
    }
    __syncthreads();
    for (int i = tid; i < 28 * C; i += 256) {
        const int e = i / C, o = i % C;
        float s = 0.0f;
        for (int d = 0; d < 28; ++d) s = fmaf(att[d][e], proj_w[(base + d) * C + o], s);
        Mb[b * (C * C) + (base + e) * C + o] = s;
    }
}

// ---------------- pe branch: g = gelu(dw3(v)) — 4px/thread window ----------
__global__ __launch_bounds__(256, 4) void k_pe1(const float* __restrict__ v,
                                                const float* __restrict__ pw1T,
                                                float* __restrict__ g) {
    const int gg = threadIdx.x >> 5, cs = threadIdx.x & 31;
    if (cs >= 28) return;
    const int c = cs * 4;
    const long px0 = (long)blockIdx.x * 32 + gg * 4;
    const int within = (int)(px0 & 65535);
    const long bb = px0 - within;
    const int r = within >> 8, w0 = within & 255;
    float4 wt[9];
#pragma unroll
    for (int t = 0; t < 9; ++t) wt[t] = *(const float4*)&pw1T[t * C + c];
    float4 acc[4];
#pragma unroll
    for (int p = 0; p < 4; ++p) acc[p] = make_float4(0.f, 0.f, 0.f, 0.f);

    if (w0 >= 4 && w0 <= 248) {
#pragma unroll
        for (int ky = 0; ky < 3; ++ky) {
            const int rr = r + ky - 1;
            if (rr < 0 || rr > 255) continue;
            const float* row = v + (bb + (rr << 8) + w0 - 1) * C + c;
            float4 win[6];
#pragma unroll
            for (int k = 0; k < 6; ++k) win[k] = *(const float4*)(row + k * C);
#pragma unroll
            for (int kx = 0; kx < 3; ++kx) {
                const float4 w4 = wt[ky * 3 + kx];
#pragma unroll
                for (int p = 0; p < 4; ++p) {
                    acc[p].x = fmaf(win[p + kx].x, w4.x, acc[p].x);
                    acc[p].y = fmaf(win[p + kx].y, w4.y, acc[p].y);
                    acc[p].z = fmaf(win[p + kx].z, w4.z, acc[p].z);
                    acc[p].w = fmaf(win[p + kx].w, w4.w, acc[p].w);
                }
            }
        }
    } else {
#pragma unroll
        for (int p = 0; p < 4; ++p) {
            const int w = w0 + p;
            for (int ky = 0; ky < 3; ++ky) {
                const int rr = r + ky - 1;
                if (rr < 0 || rr > 255) continue;
                for (int kx = 0; kx < 3; ++kx) {
                    const int ww = w + kx - 1;
                    if (ww < 0 || ww > 255) continue;
                    const float4 t = *(const float4*)&v[(bb + (rr << 8) + ww) * C + c];
                    const float4 w4 = wt[ky * 3 + kx];
                    acc[p].x = fmaf(t.x, w4.x, acc[p].x);
                    acc[p].y = fmaf(t.y, w4.y, acc[p].y);
                    acc[p].z = fmaf(t.z, w4.z, acc[p].z);
                    acc[p].w = fmaf(t.w, w4.w, acc[p].w);
                }
            }
        }
    }
#pragma unroll
    for (int p = 0; p < 4; ++p) {
        float4 a = acc[p];
        a.x = 0.5f * a.x * (1.0f + erff(a.x * 0.70710678118654752f));
        a.y = 0.5f * a.y * (1.0f + erff(a.y * 0.70710678118654752f));
        a.z = 0.5f * a.z * (1.0f + erff(a.z * 0.70710678118654752f));
        a.w = 0.5f * a.w * (1.0f + erff(a.w * 0.70710678118654752f));
        *(float4*)&g[(px0 + p) * C + c] = a;
    }
}

// ---------------- pe branch: out += dw3(g) — 4px/thread window -------------
__global__ __launch_bounds__(256, 4) void k_pe2(const float* __restrict__ g,
                                                const float* __restrict__ pw2T,
                                                float* __restrict__ out) {
    const int gg = threadIdx.x >> 5, cs = threadIdx.x & 31;
    if (cs >= 28) return;
    const int c = cs * 4;
    const long px0 = (long)blockIdx.x * 32 + gg * 4;
    const int within = (int)(px0 & 65535);
    const long bb = px0 - within;
    const int r = within >> 8, w0 = within & 255;
    float4 wt[9];
#pragma unroll
    for (int t = 0; t < 9; ++t) wt[t] = *(const float4*)&pw2T[t * C + c];
    float4 acc[4];
#pragma unroll
    for (int p = 0; p < 4; ++p) acc[p] = make_float4(0.f, 0.f, 0.f, 0.f);

    if (w0 >= 4 && w0 <= 248) {
#pragma unroll
        for (int ky = 0; ky < 3; ++ky) {
            const int rr = r + ky - 1;
            if (rr < 0 || rr > 255) continue;
            const float* row = g + (bb + (rr << 8) + w0 - 1) * C + c;
            float4 win[6];
#pragma unroll
            for (int k = 0; k < 6; ++k) win[k] = *(const float4*)(row + k * C);
#pragma unroll
            for (int kx = 0; kx < 3; ++kx) {
                const float4 w4 = wt[ky * 3 + kx];
#pragma unroll
                for (int p = 0; p < 4; ++p) {
                    acc[p].x = fmaf(win[p + kx].x, w4.x, acc[p].x);
                    acc[p].y = fmaf(win[p + kx].y, w4.y, acc[p].y);
                    acc[p].z = fmaf(win[p + kx].z, w4.z, acc[p].z);
                    acc[p].w = fmaf(win[p + kx].w, w4.w, acc[p].w);
                }
            }
        }
    } else {
#pragma unroll
        for (int p = 0; p < 4; ++p) {
            const int w = w0 + p;
            for (int ky = 0; ky < 3; ++ky) {
                const int rr = r + ky - 1;
                if (rr < 0 || rr > 255) continue;
                for (int kx = 0; kx < 3; ++kx) {
                    const int ww = w + kx - 1;
                    if (ww < 0 || ww > 255) continue;
                    const float4 t = *(const float4*)&g[(bb + (rr << 8) + ww) * C + c];
                    const float4 w4 = wt[ky * 3 + kx];
                    acc[p].x = fmaf(t.x, w4.x, acc[p].x);
                    acc[p].y = fmaf(t.y, w4.y, acc[p].y);
                    acc[p].z = fmaf(t.z, w4.z, acc[p].z);
                    acc[p].w = fmaf(t.w, w4.w, acc[p].w);
                }
            }
        }
    }
#pragma unroll
    for (int p = 0; p < 4; ++p) {
        float4 o = *(const float4*)&out[(px0 + p) * C + c];
        o.x += acc[p].x; o.y += acc[p].y; o.z += acc[p].z; o.w += acc[p].w;
        *(float4*)&out[(px0 + p) * C + c] = o;
    }
}

extern "C" void kernel_launch(void* const* d_in, const int* in_sizes, int n_in,
                              void* d_out, int out_size, void* d_ws, size_t ws_size,
                              hipStream_t stream) {
    const float* x_in    = (const float*)d_in[0];
    const float* maskp   = (const float*)d_in[1];
    const float* Wq      = (const float*)d_in[2];
    const float* Wk      = (const float*)d_in[3];
    const float* Wv      = (const float*)d_in[4];
    const float* rescale = (const float*)d_in[5];
    const float* proj_w  = (const float*)d_in[6];
    const float* proj_b  = (const float*)d_in[7];
    const float* pe_w1   = (const float*)d_in[8];
    const float* pe_w2   = (const float*)d_in[9];
    const float* c1w     = (const float*)d_in[10];
    const float* c1b     = (const float*)d_in[11];
    const float* c2w     = (const float*)d_in[12];
    const float* c2b     = (const float*)d_in[13];
    const float* dww     = (const float*)d_in[14];
    const float* dwb     = (const float*)d_in[15];

    float* ws    = (float*)d_ws;
    float* v_inp = ws;                       // 29360128
    float* mbuf  = ws + 29360128;            // m1,t2,ms (also syrk partials / g)
    float* part  = mbuf;                     // 512*12544 = 6422528 (before m1)
    float* m1    = mbuf;
    float* t2    = mbuf + 13705216;
    float* ms    = mbuf + 27410432;
    float* g     = mbuf;                     // alias (mask branch done)
    float* mattn = ws + 70475776;            // 7340032
    float* S     = ws + 77815808;
    float* T1    = ws + 77865984;
    float* T2    = ws + 77916160;
    float* Mb    = ws + 77966336;
    float* c1wT  = ws + 78016512;
    float* c2wT  = ws + 78029056;
    float* dwwT  = ws + 78041600;            // 2800
    float* pw1T  = ws + 78044400;            // 1008
    float* pw2T  = ws + 78045408;            // end 78046416 floats (312.2 MB)

    k_transpose_w<<<49, 256, 0, stream>>>(c1w, c2w, dww, pe_w1, pe_w2,
                                          c1wT, c2wT, dwwT, pw1T, pw2T);
    k_gemm112<0><<<1024, 256, 0, stream>>>(x_in, Wv, nullptr, nullptr, v_inp);
    k_syrk<<<512, 256, 0, stream>>>(x_in, part);
    k_syrk_reduce<<<dim3(4, 49), 256, 0, stream>>>(part, S);
    k_gemm112<0><<<478, 256, 0, stream>>>(maskp, c1wT, c1b, nullptr, m1);
    k_gemm112<0><<<478, 256, 0, stream>>>(m1, c2wT, c2b, nullptr, t2);
    k_dw5<<<3824, 256, 0, stream>>>(m1, t2, dwwT, dwb, ms);
    k_gather<<<1024, 256, 0, stream>>>(ms, mattn);
    k_T12<<<dim3(4, 2, 7), 256, 0, stream>>>(S, Wq, Wk, T1, T2);
    k_attn<<<16, 256, 0, stream>>>(T1, T2, Wq, Wk, rescale, proj_w, Mb);
    k_pe1<<<8192, 256, 0, stream>>>(v_inp, pw1T, g);
    k_gemm112<1><<<1024, 256, 0, stream>>>(v_inp, Mb, proj_b, mattn, (float*)d_out);
    k_pe2<<<8192, 256, 0, stream>>>(g, pw2T, (float*)d_out);
    (void)in_sizes; (void)n_in; (void)out_size; (void)ws_size;
}